// Round 1
// baseline (120.366 us; speedup 1.0000x reference)
//
#include <hip/hip_runtime.h>
#include <math.h>

#define SEQ_LEN   4096
#define EMBED_DIM 2048
#define BATCH     8

// pe[s, 2k]   = sin(s * c_k)
// pe[s, 2k+1] = cos(s * c_k)
// c_k = exp(2k * -(ln(1000)/EMBED_DIM))
//
// One thread handles one float4 (= 2 sin/cos pairs) of one (s, d) position
// and loops over all BATCH batches, so each sincosf is amortized over
// 2*BATCH = 16 output elements. Memory access per wave: 64 lanes x 16B
// contiguous = fully coalesced for both load and store.

__global__ __launch_bounds__(256) void pe_add_kernel(
    const float4* __restrict__ x, float4* __restrict__ out, int nvec) {
    int idx = blockIdx.x * blockDim.x + threadIdx.x;
    if (idx >= nvec) return;

    const int D4 = EMBED_DIM / 4;          // float4s per row
    int s  = idx / D4;
    int c4 = idx - s * D4;                 // which float4 within the row
    int k0 = c4 * 2;                       // first sin/cos pair index (d = 4*c4)

    // base = -2*ln(1000)/EMBED_DIM
    const float base = -2.0f * 6.9077552789821370521f / (float)EMBED_DIM;
    float fs = (float)s;
    float c0 = expf(base * (float)k0);
    float c1 = expf(base * (float)(k0 + 1));

    float sin0, cos0, sin1, cos1;
    sincosf(fs * c0, &sin0, &cos0);
    sincosf(fs * c1, &sin1, &cos1);

    float4 pe;
    pe.x = sin0; pe.y = cos0; pe.z = sin1; pe.w = cos1;

#pragma unroll
    for (int b = 0; b < BATCH; ++b) {
        long off = (long)b * nvec + idx;
        float4 v = x[off];
        v.x += pe.x; v.y += pe.y; v.z += pe.z; v.w += pe.w;
        out[off] = v;
    }
}

extern "C" void kernel_launch(void* const* d_in, const int* in_sizes, int n_in,
                              void* d_out, int out_size, void* d_ws, size_t ws_size,
                              hipStream_t stream) {
    const float4* x = (const float4*)d_in[0];
    float4* out = (float4*)d_out;

    const int nvec = SEQ_LEN * EMBED_DIM / 4;   // per-batch float4 count
    dim3 block(256);
    dim3 grid((nvec + 255) / 256);
    pe_add_kernel<<<grid, block, 0, stream>>>(x, out, nvec);
}

// Round 3
// 117.379 us; speedup vs baseline: 1.0254x; 1.0254x over previous
//
#include <hip/hip_runtime.h>
#include <math.h>

#define SEQ_LEN   4096
#define EMBED_DIM 2048
#define BATCH     8

// out[b,s,d] = x[b,s,d] + pe[s,d]
// pe[s,2k] = sin(s*c_k), pe[s,2k+1] = cos(s*c_k), c_k = exp(-2k*ln(1000)/D)
//
// One thread owns one float4 (2 sin/cos pairs) of one (s,d) position and
// loops the 8 batches, so each trig evaluation covers 16 output elements.
// Trig via native HW instructions: v_exp_f32 (= exp2) for c_k, and
// v_sin/v_cos_f32 (input in REVOLUTIONS, explicit fract range-reduction
// per cdna4_isa §3).

__global__ __launch_bounds__(256) void pe_add_kernel(
    const float4* __restrict__ x, float4* __restrict__ out, int nvec) {
    int idx = blockIdx.x * blockDim.x + threadIdx.x;
    if (idx >= nvec) return;

    const int D4 = EMBED_DIM / 4;          // 512 float4s per row (power of 2)
    int s  = idx >> 9;                     // idx / D4
    int c4 = idx & (D4 - 1);               // idx % D4
    int k0 = c4 * 2;                       // pair index; d = 4*c4

    // c_k = exp2(k * base_log2), base_log2 = -2*log2(1000)/EMBED_DIM
    const float base_log2 = -2.0f * 9.9657842846620870436f / (float)EMBED_DIM;
    const float INV_2PI   = 0.15915494309189533577f;

    float fs = (float)s;
    float c0 = __builtin_amdgcn_exp2f(base_log2 * (float)k0);        // v_exp_f32
    float c1 = __builtin_amdgcn_exp2f(base_log2 * (float)(k0 + 1));

    // revolutions, reduced to [0,1) for v_sin/v_cos
    float r0 = fs * c0 * INV_2PI;  r0 -= floorf(r0);
    float r1 = fs * c1 * INV_2PI;  r1 -= floorf(r1);

    float4 pe;
    pe.x = __builtin_amdgcn_sinf(r0);      // sin(2*pi*r0)
    pe.y = __builtin_amdgcn_cosf(r0);
    pe.z = __builtin_amdgcn_sinf(r1);
    pe.w = __builtin_amdgcn_cosf(r1);

#pragma unroll
    for (int b = 0; b < BATCH; ++b) {
        long off = (long)b * nvec + idx;
        float4 v = x[off];
        v.x += pe.x; v.y += pe.y; v.z += pe.z; v.w += pe.w;
        out[off] = v;
    }
}

extern "C" void kernel_launch(void* const* d_in, const int* in_sizes, int n_in,
                              void* d_out, int out_size, void* d_ws, size_t ws_size,
                              hipStream_t stream) {
    const float4* x = (const float4*)d_in[0];
    float4* out = (float4*)d_out;

    const int nvec = SEQ_LEN * EMBED_DIM / 4;   // per-batch float4 count
    dim3 block(256);
    dim3 grid((nvec + 255) / 256);
    pe_add_kernel<<<grid, block, 0, stream>>>(x, out, nvec);
}

// Round 5
// 108.342 us; speedup vs baseline: 1.1110x; 1.0834x over previous
//
#include <hip/hip_runtime.h>
#include <math.h>

#define SEQ_LEN   4096
#define EMBED_DIM 2048
#define BATCH     8

// out[b,s,d] = x[b,s,d] + pe[s,d]
// pe[s,2k] = sin(s*c_k), pe[s,2k+1] = cos(s*c_k), c_k = exp(-2k*ln(1000)/D)
//
// One thread owns one float4 (2 sin/cos pairs) of one (s,d) position and
// loops the 8 batches (trig amortized 16x). Native v_exp/v_sin/v_cos.
// R5: nontemporal load/store via clang native vector type (HIP float4 is
// a struct and rejected by the builtin) — bypass L2/L3 allocation for
// both 256 MB streams to stop thrashing the 256 MiB L3.

typedef float f32x4 __attribute__((ext_vector_type(4)));

__global__ __launch_bounds__(256) void pe_add_kernel(
    const f32x4* __restrict__ x, f32x4* __restrict__ out, int nvec) {
    int idx = blockIdx.x * blockDim.x + threadIdx.x;
    if (idx >= nvec) return;

    const int D4 = EMBED_DIM / 4;          // 512 float4s per row (power of 2)
    int s  = idx >> 9;                     // idx / D4
    int c4 = idx & (D4 - 1);               // idx % D4
    int k0 = c4 * 2;                       // pair index; d = 4*c4

    // c_k = exp2(k * base_log2), base_log2 = -2*log2(1000)/EMBED_DIM
    const float base_log2 = -2.0f * 9.9657842846620870436f / (float)EMBED_DIM;
    const float INV_2PI   = 0.15915494309189533577f;

    float fs = (float)s;
    float c0 = __builtin_amdgcn_exp2f(base_log2 * (float)k0);        // v_exp_f32
    float c1 = __builtin_amdgcn_exp2f(base_log2 * (float)(k0 + 1));

    // revolutions, reduced to [0,1) for v_sin/v_cos
    float r0 = fs * c0 * INV_2PI;  r0 -= floorf(r0);
    float r1 = fs * c1 * INV_2PI;  r1 -= floorf(r1);

    f32x4 pe;
    pe.x = __builtin_amdgcn_sinf(r0);      // sin(2*pi*r0)
    pe.y = __builtin_amdgcn_cosf(r0);
    pe.z = __builtin_amdgcn_sinf(r1);
    pe.w = __builtin_amdgcn_cosf(r1);

#pragma unroll
    for (int b = 0; b < BATCH; ++b) {
        long off = (long)b * nvec + idx;
        f32x4 v = __builtin_nontemporal_load(&x[off]);
        v += pe;
        __builtin_nontemporal_store(v, &out[off]);
    }
}

extern "C" void kernel_launch(void* const* d_in, const int* in_sizes, int n_in,
                              void* d_out, int out_size, void* d_ws, size_t ws_size,
                              hipStream_t stream) {
    const f32x4* x = (const f32x4*)d_in[0];
    f32x4* out = (f32x4*)d_out;

    const int nvec = SEQ_LEN * EMBED_DIM / 4;   // per-batch float4 count
    dim3 block(256);
    dim3 grid((nvec + 255) / 256);
    pe_add_kernel<<<grid, block, 0, stream>>>(x, out, nvec);
}

// Round 6
// 85.927 us; speedup vs baseline: 1.4008x; 1.2609x over previous
//
#include <hip/hip_runtime.h>
#include <math.h>

#define SEQ_LEN   4096
#define EMBED_DIM 2048
#define BATCH     8

// out[b,s,d] = x[b,s,d] + pe[s,d]
// pe[s,2k] = sin(s*c_k), pe[s,2k+1] = cos(s*c_k), c_k = exp(-2k*ln(1000)/D)
//
// R6: flat copy-shaped kernel — one thread per float4 over the whole
// [B,S,D] tensor, no batch loop. Each wave issues exactly one contiguous
// 1KB NT load + one 1KB NT store (the proven-fast copy pattern), instead
// of 16 streams spread 32MB apart. Trig recomputed per element: per-CU
// VALU demand (~440 cyc/round) is ~14x under the HBM service time
// (~6200 cyc/round), so it stays hidden.

typedef float f32x4 __attribute__((ext_vector_type(4)));

__global__ __launch_bounds__(256) void pe_add_kernel(
    const f32x4* __restrict__ x, f32x4* __restrict__ out, int ntot) {
    int gidx = blockIdx.x * blockDim.x + threadIdx.x;
    if (gidx >= ntot) return;

    // per-batch float4 index = gidx & (S*D/4 - 1); S*D/4 = 2^21
    int s  = (gidx >> 9) & (SEQ_LEN - 1);  // row (D/4 = 512 = 2^9)
    int c4 = gidx & (EMBED_DIM / 4 - 1);   // float4 within row
    int k0 = c4 * 2;                       // first sin/cos pair index

    // c_k = exp2(k * base_log2), base_log2 = -2*log2(1000)/EMBED_DIM
    const float base_log2 = -2.0f * 9.9657842846620870436f / (float)EMBED_DIM;
    const float INV_2PI   = 0.15915494309189533577f;

    float fs = (float)s;
    float c0 = __builtin_amdgcn_exp2f(base_log2 * (float)k0);        // v_exp_f32
    float c1 = __builtin_amdgcn_exp2f(base_log2 * (float)(k0 + 1));

    // revolutions, reduced to [0,1) for v_sin/v_cos
    float r0 = fs * c0 * INV_2PI;  r0 -= floorf(r0);
    float r1 = fs * c1 * INV_2PI;  r1 -= floorf(r1);

    f32x4 pe;
    pe.x = __builtin_amdgcn_sinf(r0);      // sin(2*pi*r0)
    pe.y = __builtin_amdgcn_cosf(r0);
    pe.z = __builtin_amdgcn_sinf(r1);
    pe.w = __builtin_amdgcn_cosf(r1);

    f32x4 v = __builtin_nontemporal_load(&x[gidx]);
    v += pe;
    __builtin_nontemporal_store(v, &out[gidx]);
}

extern "C" void kernel_launch(void* const* d_in, const int* in_sizes, int n_in,
                              void* d_out, int out_size, void* d_ws, size_t ws_size,
                              hipStream_t stream) {
    const f32x4* x = (const f32x4*)d_in[0];
    f32x4* out = (f32x4*)d_out;

    const int ntot = BATCH * SEQ_LEN * EMBED_DIM / 4;   // total float4 count
    dim3 block(256);
    dim3 grid((ntot + 255) / 256);
    pe_add_kernel<<<grid, block, 0, stream>>>(x, out, ntot);
}